// Round 5
// baseline (559.070 us; speedup 1.0000x reference)
//
#include <hip/hip_runtime.h>
#include <cstdint>

// ============================================================================
// Gtu: u=silu(x@Wu+bu); v=silu(x@Wv+bv); per-channel causal conv of v with
// RPE-generated decayed kernel (rfft4096 via packed cfft2048); out=(u*conv)@Wo+bo
// R5: barrier-free per-WAVE FFT-2048 (radix 8,8,8,4; 32 pts/lane in registers,
// one 16KB in-place LDS buffer per wave, sigma(j)=j^((j>>4)&15) bank swizzle).
// 128-thr blocks (2 waves = 2 sequences), zero __syncthreads in FFT kernels.
// ============================================================================

typedef unsigned short ushort_t;                                    // bf16 bits
typedef __attribute__((ext_vector_type(8))) short short8;           // MFMA A/B frag
typedef __attribute__((ext_vector_type(4))) float f32x4;            // MFMA acc

#define AS1 __attribute__((address_space(1)))
#define AS3 __attribute__((address_space(3)))

__device__ __forceinline__ float bf2f(ushort_t b) {
  union { unsigned u; float f; } x; x.u = ((unsigned)b) << 16; return x.f;
}
__device__ __forceinline__ ushort_t f2bf(float f) {
  union { float f; unsigned u; } x; x.f = f;
  unsigned r = x.u + 0x7fffu + ((x.u >> 16) & 1u);   // RNE
  return (ushort_t)(r >> 16);
}

// CK-style addrspace cast (flat LDS addr low 32 bits == LDS offset on gfx9)
__device__ __forceinline__ void gload_lds16(const void* g, void* l) {
  auto gp = reinterpret_cast<const AS1 unsigned*>(reinterpret_cast<uintptr_t>(g));
  auto lp = reinterpret_cast<AS3 unsigned*>(reinterpret_cast<uintptr_t>(l));
  __builtin_amdgcn_global_load_lds(gp, lp, 16, 0, 0);
}

// ---------------------------------------------------------------------------
// bf16 GEMM: C = A[M][K] @ Bt[N][K]^T (+bias). 128x128x64 tiles, 4 waves.
// MODE 0: fp32 store. MODE 2: *gamma^row, fp32 transposed store (RPE kernel).
// MODE 3: silu; col<1536 -> u[row][col] bf16; col>=1536 -> vt[col-1536][row].
// ---------------------------------------------------------------------------
template<int MODE>
__launch_bounds__(256, 2)
__global__ void gemm_bt(const ushort_t* __restrict__ A, const ushort_t* __restrict__ Bt,
                        const float* __restrict__ bias, void* __restrict__ Cout,
                        void* __restrict__ Cout2, int M, int N, int K, float lng)
{
  __shared__ ushort_t As[128 * 64];
  __shared__ ushort_t Bs[128 * 64];
  const int tid  = threadIdx.x;
  const int wave = tid >> 6, lane = tid & 63;
  const int nb = N >> 7;
  const int bm = (int)blockIdx.x / nb, bn = (int)blockIdx.x % nb;
  const int m0 = bm << 7, n0 = bn << 7;
  const int lrow = lane & 15, quad = lane >> 4;
  const int wm = (wave >> 1) << 6, wn = (wave & 1) << 6;
  const int srow = lane >> 3;            // 0..7 (row within 8-row chunk)
  const int scol = (lane & 7) << 3;      // bf16 col (8-elem granules)

  f32x4 acc[4][4] = {};

  for (int kt = 0; kt < K; kt += 64) {
    __syncthreads();
#pragma unroll
    for (int i = 0; i < 4; ++i) {
      const int ci  = i * 4 + wave;      // chunk 0..15, wave-uniform
      const int row = ci * 8 + srow;
      gload_lds16(A  + (long)(m0 + row) * K + kt + scol, (void*)&As[ci * 512]);
      gload_lds16(Bt + (long)(n0 + row) * K + kt + scol, (void*)&Bs[ci * 512]);
    }
    __syncthreads();
#pragma unroll
    for (int s = 0; s < 2; ++s) {
      short8 afr[4], bfr[4];
#pragma unroll
      for (int i = 0; i < 4; ++i)
        afr[i] = *(const short8*)&As[(wm + i * 16 + lrow) * 64 + s * 32 + quad * 8];
#pragma unroll
      for (int j = 0; j < 4; ++j)
        bfr[j] = *(const short8*)&Bs[(wn + j * 16 + lrow) * 64 + s * 32 + quad * 8];
#pragma unroll
      for (int i = 0; i < 4; ++i)
#pragma unroll
        for (int j = 0; j < 4; ++j)
          acc[i][j] = __builtin_amdgcn_mfma_f32_16x16x32_bf16(afr[i], bfr[j], acc[i][j], 0, 0, 0);
    }
  }

#pragma unroll
  for (int i = 0; i < 4; ++i) {
    const int rowb = m0 + wm + i * 16 + quad * 4;
#pragma unroll
    for (int j = 0; j < 4; ++j) {
      const int col = n0 + wn + j * 16 + lrow;
      const float bv = bias[col];
      if (MODE == 0) {
#pragma unroll
        for (int r = 0; r < 4; ++r)
          ((float*)Cout)[(long)(rowb + r) * N + col] = acc[i][j][r] + bv;
      } else if (MODE == 2) {
#pragma unroll
        for (int r = 0; r < 4; ++r) {
          const int row = rowb + r;
          float dec = __expf(lng * (float)row);           // gamma^row
          ((float*)Cout)[(long)col * M + row] = (acc[i][j][r] + bv) * dec;
        }
      } else {  // MODE 3
        if (col < 1536) {
#pragma unroll
          for (int r = 0; r < 4; ++r) {
            float val = acc[i][j][r] + bv;
            float sv = val / (1.f + __expf(-val));
            ((ushort_t*)Cout)[(long)(rowb + r) * 1536 + col] = f2bf(sv);
          }
        } else {
          union { ushort_t h[4]; uint2 u2; } pk;
#pragma unroll
          for (int r = 0; r < 4; ++r) {
            float val = acc[i][j][r] + bv;
            float sv = val / (1.f + __expf(-val));
            pk.h[r] = f2bf(sv);
          }
          *(uint2*)((ushort_t*)Cout2 + (long)(col - 1536) * 16384 + rowb) = pk.u2;
        }
      }
    }
  }
}

// ---------------------------------------------------------------------------
// RPE row op: srms -> relu -> bf16 (one 256-thr block per row of 512)
// ---------------------------------------------------------------------------
__device__ __forceinline__ void srms_relu_store(float v0, float v1, ushort_t* out,
                                                long rowbase, int tid)
{
  float ss = v0 * v0 + v1 * v1;
#pragma unroll
  for (int off = 32; off; off >>= 1) ss += __shfl_down(ss, off);
  __shared__ float ps[4];
  const int wave = tid >> 6, lane = tid & 63;
  if (lane == 0) ps[wave] = ss;
  __syncthreads();
  float tot = ps[0] + ps[1] + ps[2] + ps[3];
  float sc = 1.f / (sqrtf(tot * (1.f / 512.f)) + 1e-6f);
  out[rowbase + tid]       = f2bf(fmaxf(v0 * sc, 0.f));
  out[rowbase + tid + 256] = f2bf(fmaxf(v1 * sc, 0.f));
}

__launch_bounds__(256)
__global__ void rpe_norm(const float* __restrict__ h, ushort_t* __restrict__ out)
{
  const int n = blockIdx.x, tid = threadIdx.x;
  float v0 = h[(long)n * 512 + tid];
  float v1 = h[(long)n * 512 + tid + 256];
  srms_relu_store(v0, v1, out, (long)n * 512, tid);
}

// ---------------------------------------------------------------------------
// Merged prep: 6x weight transpose | bias concat | x->bf16 | twiddles | rpe_h0
// ---------------------------------------------------------------------------
__device__ __forceinline__ void wtrans_body(const float* __restrict__ src,
                                            ushort_t* __restrict__ dst,
                                            int K, int N, int lb, int tid,
                                            float (*tile)[33])
{
  const int nbx = N >> 5;
  const int bx = lb % nbx, by = lb / nbx;
  const int n0 = bx << 5, k0 = by << 5;
  const int tx = tid & 31, ty = tid >> 5;
  for (int yy = ty; yy < 32; yy += 8)
    tile[yy][tx] = src[(long)(k0 + yy) * N + n0 + tx];
  __syncthreads();
  for (int yy = ty; yy < 32; yy += 8)
    dst[(long)(n0 + yy) * K + k0 + tx] = f2bf(tile[tx][yy]);
}

__launch_bounds__(256)
__global__ void prep_all(const float* __restrict__ Wu, const float* __restrict__ Wv,
                         const float* __restrict__ Wo, const float* __restrict__ rW,
                         const float* __restrict__ rWout,
                         const float* __restrict__ bu, const float* __restrict__ bv,
                         const float* __restrict__ x,
                         const float* __restrict__ rWin, const float* __restrict__ rbin,
                         ushort_t* __restrict__ wuvt, ushort_t* __restrict__ wot,
                         ushort_t* __restrict__ wrt, ushort_t* __restrict__ wroutt,
                         float* __restrict__ buvb, ushort_t* __restrict__ xb,
                         float2* __restrict__ twg, float2* __restrict__ twh,
                         ushort_t* __restrict__ a0)
{
  __shared__ float tile[32][33];
  const int bid = blockIdx.x, tid = threadIdx.x;
  if (bid < 3840) {                       // ---- weight transposes ----
    const float* src; ushort_t* dst; int K, N, lb;
    if (bid < 768)       { src = Wu;    dst = wuvt;              K = 512;  N = 1536; lb = bid; }
    else if (bid < 1536) { src = Wv;    dst = wuvt + 1536L*512;  K = 512;  N = 1536; lb = bid - 768; }
    else if (bid < 2304) { src = Wo;    dst = wot;               K = 1536; N = 512;  lb = bid - 1536; }
    else if (bid < 2560) { src = rW;              dst = wrt;              K = 512; N = 512; lb = bid - 2304; }
    else if (bid < 2816) { src = rW + 512L*512;   dst = wrt + 512L*512;   K = 512; N = 512; lb = bid - 2560; }
    else if (bid < 3072) { src = rW + 2L*512*512; dst = wrt + 2L*512*512; K = 512; N = 512; lb = bid - 2816; }
    else                 { src = rWout; dst = wroutt;            K = 512;  N = 1536; lb = bid - 3072; }
    wtrans_body(src, dst, K, N, lb, tid, tile);
  } else if (bid < 3846) {                // ---- bias concat ----
    int i = (bid - 3840) * 256 + tid;
    if (i < 1536) { buvb[i] = bu[i]; buvb[1536 + i] = bv[i]; }
  } else if (bid < 12038) {               // ---- x -> bf16 ----
    long i = (long)(bid - 3846) * 1024 + tid * 4;
    float4 f = *(const float4*)(x + i);
    unsigned lo = (unsigned)f2bf(f.x) | ((unsigned)f2bf(f.y) << 16);
    unsigned hi = (unsigned)f2bf(f.z) | ((unsigned)f2bf(f.w) << 16);
    *(uint2*)(xb + i) = make_uint2(lo, hi);
  } else if (bid < 12046) {               // ---- twiddle tables ----
    int j = (bid - 12038) * 256 + tid;    // 0..2047
    float s, c;
    __sincosf((float)j * (6.283185307179586f / 2048.f), &s, &c);
    twg[j] = make_float2(c, -s);
    if (j <= 1024) {
      float s2, c2;
      __sincosf((float)j * (3.14159265358979f / 2048.f), &s2, &c2);
      twh[j] = make_float2(c2, -s2);
    }
  } else {                                // ---- rpe_h0 ----
    const int n = bid - 12046;            // 0..2047
    const float fn = (float)n;
    float v0 = fn * rWin[tid] + rbin[tid];
    float v1 = fn * rWin[tid + 256] + rbin[tid + 256];
    srms_relu_store(v0, v1, a0, (long)n * 512, tid);
  }
}

// ---------------------------------------------------------------------------
// Per-wave in-place FFT-2048 (radix 8,8,8,4 Stockham), 64 lanes, 32 pts/lane.
// Slot swizzle sigma(j) = j ^ ((j>>4)&15). For j = l + 64t:
//   sigma = (lam ^ (4t&12)) + 64t,  lam = l ^ (l>>4)   -> 4 base ptrs + imm.
// No barriers: intra-wave lockstep + lgkmcnt ordering make in-place safe
// (all of a stage's reads are issued before any of its writes).
// ---------------------------------------------------------------------------
__device__ __forceinline__ float2 cmulf(float2 a, float2 b) {
  return make_float2(a.x * b.x - a.y * b.y, a.x * b.y + a.y * b.x);
}
__device__ __forceinline__ float2 cadd(float2 a, float2 b){ return make_float2(a.x+b.x, a.y+b.y); }
__device__ __forceinline__ float2 csub(float2 a, float2 b){ return make_float2(a.x-b.x, a.y-b.y); }
__device__ __forceinline__ float2 cmni(float2 z){ return make_float2(z.y, -z.x); }     // z * (-i)
__device__ __forceinline__ float2 cw8(float2 z){   // z * cis(-pi/4)
  const float s = 0.70710678118654752f;
  return make_float2(s*(z.x+z.y), s*(z.y-z.x));
}
__device__ __forceinline__ float2 cw83(float2 z){  // z * cis(-3pi/4)
  const float s = 0.70710678118654752f;
  return make_float2(s*(z.y-z.x), -s*(z.x+z.y));
}

// DFT-8 combine (twiddles pre-applied). y[n] = sum_m u[m] w8^{nm}   [R4-verified]
__device__ __forceinline__ void dft8(const float2* u, float2* y)
{
  float2 a0=cadd(u[0],u[4]), a1=cadd(u[1],u[5]), a2=cadd(u[2],u[6]), a3=cadd(u[3],u[7]);
  float2 b0=csub(u[0],u[4]), b1=cw8(csub(u[1],u[5])), b2=cmni(csub(u[2],u[6])), b3=cw83(csub(u[3],u[7]));
  float2 c0=cadd(a0,a2), c1=csub(a0,a2), c2=cadd(a1,a3), c3=cmni(csub(a1,a3));
  y[0]=cadd(c0,c2); y[2]=cadd(c1,c3); y[4]=csub(c0,c2); y[6]=csub(c1,c3);
  float2 d0=cadd(b0,b2), d1=csub(b0,b2), d2=cadd(b1,b3), d3=cmni(csub(b1,b3));
  y[1]=cadd(d0,d2); y[3]=cadd(d1,d3); y[5]=csub(d0,d2); y[7]=csub(d1,d3);
}
// DFT-8 with u[4..7]=0   [R4-verified]
__device__ __forceinline__ void dft8_hz(const float2* u, float2* y)
{
  float2 b1=cw8(u[1]), b2=cmni(u[2]), b3=cw83(u[3]);
  float2 c0=cadd(u[0],u[2]), c1=csub(u[0],u[2]), c2=cadd(u[1],u[3]), c3=cmni(csub(u[1],u[3]));
  y[0]=cadd(c0,c2); y[2]=cadd(c1,c3); y[4]=csub(c0,c2); y[6]=csub(c1,c3);
  float2 d0=cadd(u[0],b2), d1=csub(u[0],b2), d2=cadd(b1,b3), d3=cmni(csub(b1,b3));
  y[1]=cadd(d0,d2); y[3]=cadd(d1,d3); y[5]=csub(d0,d2); y[7]=csub(d1,d3);
}

#define MKBP(B, lam) { (B) + (lam), (B) + ((lam) ^ 4), (B) + ((lam) ^ 8), (B) + ((lam) ^ 12) }

template<bool HZ>
__device__ void fft2048_wave(float2* B, const float2* __restrict__ tw, int l)
{
  const int lam = l ^ (l >> 4);
  float2* const Bp[4] = MKBP(B, lam);
  float2 y[8];
  // ---- stage 1: radix-8, p=1 (no twiddles) ----
  {
    float2 U[4][8];
#pragma unroll
    for (int q = 0; q < 4; ++q)
#pragma unroll
      for (int m = 0; m < (HZ ? 4 : 8); ++m) {
        const int t = q + 4 * m;                  // j = l + 64t
        U[q][m] = Bp[t & 3][64 * t];
      }
    const int mask1 = (l >> 1) & 15;
    const int s1base = (l << 3) ^ (mask1 & 8);
    const int mlow = mask1 & 7;
#pragma unroll
    for (int q = 0; q < 4; ++q) {
      if (HZ) dft8_hz(U[q], y); else dft8(U[q], y);
#pragma unroll
      for (int m = 0; m < 8; ++m)
        B[s1base + 512 * q + (m ^ mlow)] = y[m];   // sigma(8l+512q+m)
    }
  }
  // ---- stage 2: radix-8, p=8 ----
  {
    float2 U[4][8];
#pragma unroll
    for (int q = 0; q < 4; ++q)
#pragma unroll
      for (int m = 0; m < 8; ++m) {
        const int t = q + 4 * m;
        U[q][m] = Bp[t & 3][64 * t];
      }
    const int k0 = l & 7;
    float2 w[8];
#pragma unroll
    for (int m = 1; m < 8; ++m) w[m] = tw[32 * k0 * m];
    const int jb = ((l >> 3) << 6) + k0;           // 64a + k0
    const int mask2 = ((l >> 3) & 3) << 2;         // 4*(a&3)
#pragma unroll
    for (int q = 0; q < 4; ++q) {
#pragma unroll
      for (int m = 1; m < 8; ++m) U[q][m] = cmulf(U[q][m], w[m]);
      dft8(U[q], y);
#pragma unroll
      for (int m = 0; m < 8; ++m)
        B[(jb + 8 * m + 512 * q) ^ (mask2 ^ (m >> 1))] = y[m];
    }
  }
  // ---- stage 3: radix-8, p=64 (k = l) ----
  {
    float2 U[4][8];
#pragma unroll
    for (int q = 0; q < 4; ++q)
#pragma unroll
      for (int m = 0; m < 8; ++m) {
        const int t = q + 4 * m;
        U[q][m] = Bp[t & 3][64 * t];
      }
    float2 w[8];
#pragma unroll
    for (int m = 1; m < 8; ++m) w[m] = tw[4 * l * m];
#pragma unroll
    for (int q = 0; q < 4; ++q) {
#pragma unroll
      for (int m = 1; m < 8; ++m) U[q][m] = cmulf(U[q][m], w[m]);
      dft8(U[q], y);
      // j = l + 64*(m + 8q): t = m + 8q, t&3 = m&3
#pragma unroll
      for (int m = 0; m < 8; ++m)
        Bp[m & 3][64 * (m + 8 * q)] = y[m];
    }
  }
  // ---- stage 4: radix-4, p=512 (k=i, j=i; slots partitioned per lane) ----
#pragma unroll
  for (int q = 0; q < 8; ++q) {
    float2 V[4];
#pragma unroll
    for (int m = 0; m < 4; ++m)
      V[m] = Bp[q & 3][64 * (q + 8 * m)];          // j = l + 64*(q+8m)
    const int i = l + 64 * q;
    float2 q1 = cmulf(V[1], tw[i]);
    float2 q2 = cmulf(V[2], tw[2 * i]);
    float2 q3 = cmulf(V[3], tw[3 * i]);
    float2 v0 = cadd(V[0], q2), v2 = csub(V[0], q2);
    float2 v1 = cadd(q1, q3),   v3 = cmni(csub(q1, q3));
    Bp[q & 3][64 * q]        = cadd(v0, v1);
    Bp[q & 3][64 * (q + 8)]  = cadd(v2, v3);
    Bp[q & 3][64 * (q + 16)] = csub(v0, v1);
    Bp[q & 3][64 * (q + 24)] = csub(v2, v3);
  }
}

// Kernel spectrum: af[c][k] = rfft_4096(kern[c][0:2048] zero-padded), k=0..2048
__launch_bounds__(128)
__global__ void fft_kernel_spec(const float* __restrict__ kern, float2* __restrict__ af,
                                const float2* __restrict__ twg, const float2* __restrict__ twh)
{
  __shared__ float2 buf[2][2048];
  const int tid = threadIdx.x, wid = tid >> 6, l = tid & 63;
  const int c = (int)blockIdx.x * 2 + wid;
  float2* B = buf[wid];
  const int lam = l ^ (l >> 4);
  float2* const Bp[4] = MKBP(B, lam);
  const float* kc = kern + (long)c * 2048;
#pragma unroll
  for (int t = 0; t < 16; ++t)
    Bp[t & 3][64 * t] = *(const float2*)(kc + 2 * (l + 64 * t));
  fft2048_wave<true>(B, twg, l);
  float2* afc = af + (long)c * 2052;
#pragma unroll
  for (int t = 0; t <= 16; ++t) {
    const int k = l + 64 * t;
    if (k <= 1024) {
      float2 Zk = Bp[t & 3][64 * t];
      const int jn = (2048 - k) & 2047;
      float2 Zn = B[jn ^ ((jn >> 4) & 15)];
      float2 E = make_float2(0.5f * (Zk.x + Zn.x), 0.5f * (Zk.y - Zn.y));
      float2 O = make_float2(0.5f * (Zk.y + Zn.y), 0.5f * (Zn.x - Zk.x));
      float2 W = twh[k];
      float2 WO = cmulf(W, O);
      afc[k] = make_float2(E.x + WO.x, E.y + WO.y);
      if (k != 0 && k != 1024)
        afc[2048 - k] = make_float2(E.x - WO.x, -(E.y - WO.y));
      if (k == 0)
        afc[2048] = make_float2(E.x - WO.x, -(E.y - WO.y));
    }
  }
}

// Conv (IN PLACE on vt): y = irfft4096(rfft4096(v)*af)[0:2048]; wave=(c,b) seq
__launch_bounds__(128)
__global__ void fft_conv(ushort_t* __restrict__ vt, const float2* __restrict__ af,
                         const float2* __restrict__ twg, const float2* __restrict__ twh)
{
  __shared__ float2 buf[2][2048];
  const int tid = threadIdx.x, wid = tid >> 6, l = tid & 63;
  const long s = (long)blockIdx.x * 2 + wid;      // 0..12287
  const int c = (int)(s >> 3);
  float2* B = buf[wid];
  const int lam = l ^ (l >> 4);
  float2* const Bp[4] = MKBP(B, lam);
  ushort_t* vs = vt + s * 2048;
#pragma unroll
  for (int t = 0; t < 16; ++t) {
    unsigned pv = *(const unsigned*)(vs + 2 * (l + 64 * t));
    Bp[t & 3][64 * t] = make_float2(bf2f((ushort_t)(pv & 0xffffu)), bf2f((ushort_t)(pv >> 16)));
  }
  fft2048_wave<true>(B, twg, l);                  // B = Z (packed fwd FFT)
  const float2* afc = af + (long)c * 2052;
#pragma unroll
  for (int t = 0; t <= 16; ++t) {
    const int k = l + 64 * t;
    if (k <= 1024) {
      float2 Zk = Bp[t & 3][64 * t];
      const int jn = (2048 - k) & 2047;
      const int sjn = jn ^ ((jn >> 4) & 15);
      float2 Zn = B[sjn];
      float2 E = make_float2(0.5f * (Zk.x + Zn.x), 0.5f * (Zk.y - Zn.y));
      float2 O = make_float2(0.5f * (Zk.y + Zn.y), 0.5f * (Zn.x - Zk.x));
      float2 W = twh[k];
      float2 WO = cmulf(W, O);
      float2 Xk = make_float2(E.x + WO.x, E.y + WO.y);          // rfft(v)[k]
      float2 Xn = make_float2(E.x - WO.x, -(E.y - WO.y));       // rfft(v)[2048-k]
      float2 Pk = cmulf(Xk, afc[k]);
      float2 Pn = cmulf(Xn, afc[2048 - k]);
      // E2=(Pk+conj(Pn))/2, G=(Pk-conj(Pn))/2, Fo=conj(W)*G, W2=E2+i*Fo
      float2 E2 = make_float2(0.5f * (Pk.x + Pn.x), 0.5f * (Pk.y - Pn.y));
      float2 G  = make_float2(0.5f * (Pk.x - Pn.x), 0.5f * (Pk.y + Pn.y));
      float2 cW = make_float2(W.x, -W.y);
      float2 Fo = cmulf(cW, G);
      Bp[t & 3][64 * t] = make_float2(E2.x - Fo.y, -(E2.y + Fo.x));   // conj(W2[k])
      if (k != 0 && k != 1024)
        B[sjn] = make_float2(E2.x + Fo.y, E2.y - Fo.x);               // conj(W2[2048-k])
    }
  }
  fft2048_wave<false>(B, twg, l);                 // B = FFT(conj(W2))
  const float inv = 1.f / 2048.f;
#pragma unroll
  for (int t = 0; t < 16; ++t) {                  // z[j]=conj(B[j])/2048
    float2 r = Bp[t & 3][64 * t];
    unsigned ov = (unsigned)f2bf(r.x * inv) | ((unsigned)f2bf(-r.y * inv) << 16);
    *(unsigned*)(vs + 2 * (l + 64 * t)) = ov;
  }
}

// gate IN PLACE: u[bn][c] *= conv[c][bn]   (conv lives in vt)
__launch_bounds__(256)
__global__ void gate_trans(const ushort_t* __restrict__ convt, ushort_t* __restrict__ u)
{
  __shared__ ushort_t tile[64][65];
  const int bc = (int)blockIdx.x % 24, br = (int)blockIdx.x / 24;
  const int c0 = bc << 6, r0 = br << 6;
  const int tx = threadIdx.x & 63, ty = threadIdx.x >> 6;
  for (int yy = ty; yy < 64; yy += 4)
    tile[yy][tx] = convt[(long)(c0 + yy) * 16384 + r0 + tx];
  __syncthreads();
  for (int yy = ty; yy < 64; yy += 4) {
    long ui = (long)(r0 + yy) * 1536 + c0 + tx;
    float uu = bf2f(u[ui]);
    float cc = bf2f(tile[tx][yy]);
    u[ui] = f2bf(uu * cc);
  }
}

// ===========================================================================
extern "C" void kernel_launch(void* const* d_in, const int* in_sizes, int n_in,
                              void* d_out, int out_size, void* d_ws, size_t ws_size,
                              hipStream_t stream)
{
  const float* x     = (const float*)d_in[0];
  const float* Wu    = (const float*)d_in[1];
  const float* bu    = (const float*)d_in[2];
  const float* Wv    = (const float*)d_in[3];
  const float* bv    = (const float*)d_in[4];
  const float* Wo    = (const float*)d_in[5];
  const float* bo    = (const float*)d_in[6];
  const float* rWin  = (const float*)d_in[7];
  const float* rbin  = (const float*)d_in[8];
  const float* rW    = (const float*)d_in[9];
  const float* rb    = (const float*)d_in[10];
  const float* rWout = (const float*)d_in[11];
  const float* rbout = (const float*)d_in[12];

  char* base = (char*)d_ws;
  size_t off = 0;
  auto alloc = [&](size_t bytes) -> char* {
    size_t r = (off + 255) & ~(size_t)255; off = r + bytes; return base + r;
  };
  ushort_t* wuvt   = (ushort_t*)alloc(3072L * 512 * 2);     // [Wu^T; Wv^T]  3MB
  ushort_t* wot    = (ushort_t*)alloc(512L * 1536 * 2);     // Wo^T        1.5MB
  ushort_t* wrt    = (ushort_t*)alloc(3L * 512 * 512 * 2);  // rpe_W^T x3  1.5MB
  ushort_t* wroutt = (ushort_t*)alloc(1536L * 512 * 2);     // rpe_Wout^T  1.5MB
  float*    buvb   = (float*)   alloc(3072L * 4);           // [bu;bv]
  ushort_t* a0     = (ushort_t*)alloc(2048L * 512 * 2);     // RPE act bf16  2MB
  float2*   af     = (float2*)  alloc(1536L * 2052 * 8);    // spectra    25.2MB
  float2*   twg    = (float2*)  alloc(2048L * 8);           // cis(-2pi j/2048)
  float2*   twh    = (float2*)  alloc(1025L * 8);           // cis(-pi k/2048)
  char*     X      = alloc(16384L * 512 * 2);               // xb | (h+kern) 16MB
  ushort_t* u      = (ushort_t*)alloc(16384L * 1536 * 2);   // u (later gated) 48MB
  ushort_t* vt     = (ushort_t*)alloc(1536L * 16384 * 2);   // v^T / conv^T  48MB
  ushort_t* xb   = (ushort_t*)X;
  float*    h    = (float*)X;
  float*    kern = (float*)(X + 4L * 1024 * 1024);

  const float lng = -0.01005033585350145f;   // ln(0.99)

  // ---- merged prep: weights, biases, x->bf16, twiddles, rpe_h0 ----
  prep_all<<<dim3(14094), dim3(256), 0, stream>>>(
      Wu, Wv, Wo, rW, rWout, bu, bv, x, rWin, rbin,
      wuvt, wot, wrt, wroutt, buvb, xb, twg, twh, a0);

  // ---- u/v projection (fused, v stored transposed) ----
  gemm_bt<3><<<dim3(3072), dim3(256), 0, stream>>>(xb, wuvt, buvb, u, vt,
                                                   16384, 3072, 512, 0.f);

  // ---- RPE chain -> kern[c][n] -> spectra af ----
  for (int i = 0; i < 3; ++i) {
    gemm_bt<0><<<dim3(64), dim3(256), 0, stream>>>(a0, wrt + (long)i * 512 * 512,
                                                   rb + (long)i * 512, h, nullptr,
                                                   2048, 512, 512, 0.f);
    rpe_norm<<<dim3(2048), dim3(256), 0, stream>>>(h, a0);
  }
  gemm_bt<2><<<dim3(192), dim3(256), 0, stream>>>(a0, wroutt, rbout, kern, nullptr,
                                                  2048, 1536, 512, lng);
  fft_kernel_spec<<<dim3(768), dim3(128), 0, stream>>>(kern, af, twg, twh);

  // ---- FFT conv in place on vt, gate in place into u, out projection ----
  fft_conv<<<dim3(6144), dim3(128), 0, stream>>>(vt, af, twg, twh);
  gate_trans<<<dim3(6144), dim3(256), 0, stream>>>(vt, u);
  gemm_bt<0><<<dim3(512), dim3(256), 0, stream>>>(u, wot, bo, d_out, nullptr,
                                                  16384, 512, 1536, 0.f);
}

// Round 7
// 493.037 us; speedup vs baseline: 1.1339x; 1.1339x over previous
//
#include <hip/hip_runtime.h>
#include <cstdint>

// ============================================================================
// Gtu: u=silu(x@Wu+bu); v=silu(x@Wv+bv); per-channel causal conv of v with
// RPE-generated decayed kernel (rfft4096 via packed cfft2048); out=(u*conv)@Wo+bo
// R7: revert FFT to R4's HW-verified block-level radix-8,8,8,4 implementation,
// but process TWO sequences per block (duplicated registers, shared twiddles,
// one barrier set for both) -> half the barriers/seq, 2x ILP. RPE small GEMMs
// moved to 64x64 tiles (256/768 blocks vs 64/192).
// ============================================================================

typedef unsigned short ushort_t;                                    // bf16 bits
typedef __attribute__((ext_vector_type(8))) short short8;           // MFMA A/B frag
typedef __attribute__((ext_vector_type(4))) float f32x4;            // MFMA acc

#define AS1 __attribute__((address_space(1)))
#define AS3 __attribute__((address_space(3)))

// per-buffer swizzles (bijections on [0,2048) float2 indices) [R4 HW-verified]
#define SW1(j) ((j) ^ (((j) >> 4) & 15))        // stage1-output buffer
#define SW2(j) ((j) ^ ((((j) >> 6) & 7) << 1))  // stage2-output buffer

__device__ __forceinline__ float bf2f(ushort_t b) {
  union { unsigned u; float f; } x; x.u = ((unsigned)b) << 16; return x.f;
}
__device__ __forceinline__ ushort_t f2bf(float f) {
  union { float f; unsigned u; } x; x.f = f;
  unsigned r = x.u + 0x7fffu + ((x.u >> 16) & 1u);   // RNE
  return (ushort_t)(r >> 16);
}

// CK-style addrspace cast (flat LDS addr low 32 bits == LDS offset on gfx9)
__device__ __forceinline__ void gload_lds16(const void* g, void* l) {
  auto gp = reinterpret_cast<const AS1 unsigned*>(reinterpret_cast<uintptr_t>(g));
  auto lp = reinterpret_cast<AS3 unsigned*>(reinterpret_cast<uintptr_t>(l));
  __builtin_amdgcn_global_load_lds(gp, lp, 16, 0, 0);
}

// ---------------------------------------------------------------------------
// bf16 GEMM: C = A[M][K] @ Bt[N][K]^T (+bias). 128x128x64 tiles, 4 waves.
// MODE 0: fp32 store. MODE 3: silu; col<1536 -> u; col>=1536 -> vt transposed.
// ---------------------------------------------------------------------------
template<int MODE>
__launch_bounds__(256, 2)
__global__ void gemm_bt(const ushort_t* __restrict__ A, const ushort_t* __restrict__ Bt,
                        const float* __restrict__ bias, void* __restrict__ Cout,
                        void* __restrict__ Cout2, int M, int N, int K, float lng)
{
  __shared__ ushort_t As[128 * 64];
  __shared__ ushort_t Bs[128 * 64];
  const int tid  = threadIdx.x;
  const int wave = tid >> 6, lane = tid & 63;
  const int nb = N >> 7;
  const int bm = (int)blockIdx.x / nb, bn = (int)blockIdx.x % nb;
  const int m0 = bm << 7, n0 = bn << 7;
  const int lrow = lane & 15, quad = lane >> 4;
  const int wm = (wave >> 1) << 6, wn = (wave & 1) << 6;
  const int srow = lane >> 3;
  const int scol = (lane & 7) << 3;

  f32x4 acc[4][4] = {};

  for (int kt = 0; kt < K; kt += 64) {
    __syncthreads();
#pragma unroll
    for (int i = 0; i < 4; ++i) {
      const int ci  = i * 4 + wave;
      const int row = ci * 8 + srow;
      gload_lds16(A  + (long)(m0 + row) * K + kt + scol, (void*)&As[ci * 512]);
      gload_lds16(Bt + (long)(n0 + row) * K + kt + scol, (void*)&Bs[ci * 512]);
    }
    __syncthreads();
#pragma unroll
    for (int s = 0; s < 2; ++s) {
      short8 afr[4], bfr[4];
#pragma unroll
      for (int i = 0; i < 4; ++i)
        afr[i] = *(const short8*)&As[(wm + i * 16 + lrow) * 64 + s * 32 + quad * 8];
#pragma unroll
      for (int j = 0; j < 4; ++j)
        bfr[j] = *(const short8*)&Bs[(wn + j * 16 + lrow) * 64 + s * 32 + quad * 8];
#pragma unroll
      for (int i = 0; i < 4; ++i)
#pragma unroll
        for (int j = 0; j < 4; ++j)
          acc[i][j] = __builtin_amdgcn_mfma_f32_16x16x32_bf16(afr[i], bfr[j], acc[i][j], 0, 0, 0);
    }
  }

#pragma unroll
  for (int i = 0; i < 4; ++i) {
    const int rowb = m0 + wm + i * 16 + quad * 4;
#pragma unroll
    for (int j = 0; j < 4; ++j) {
      const int col = n0 + wn + j * 16 + lrow;
      const float bv = bias[col];
      if (MODE == 0) {
#pragma unroll
        for (int r = 0; r < 4; ++r)
          ((float*)Cout)[(long)(rowb + r) * N + col] = acc[i][j][r] + bv;
      } else {  // MODE 3
        if (col < 1536) {
#pragma unroll
          for (int r = 0; r < 4; ++r) {
            float val = acc[i][j][r] + bv;
            float sv = val / (1.f + __expf(-val));
            ((ushort_t*)Cout)[(long)(rowb + r) * 1536 + col] = f2bf(sv);
          }
        } else {
          union { ushort_t h[4]; uint2 u2; } pk;
#pragma unroll
          for (int r = 0; r < 4; ++r) {
            float val = acc[i][j][r] + bv;
            float sv = val / (1.f + __expf(-val));
            pk.h[r] = f2bf(sv);
          }
          *(uint2*)((ushort_t*)Cout2 + (long)(col - 1536) * 16384 + rowb) = pk.u2;
        }
      }
    }
  }
}

// ---------------------------------------------------------------------------
// Small-GEMM variant: 64x64 tiles, 4 waves (each 32x32). Same staging scheme.
// MODE 0: fp32 store. MODE 2: *gamma^row, transposed fp32 store (RPE kernel).
// ---------------------------------------------------------------------------
template<int MODE>
__launch_bounds__(256, 2)
__global__ void gemm64_bt(const ushort_t* __restrict__ A, const ushort_t* __restrict__ Bt,
                          const float* __restrict__ bias, float* __restrict__ Cout,
                          int M, int N, int K, float lng)
{
  __shared__ ushort_t As[64 * 64];
  __shared__ ushort_t Bs[64 * 64];
  const int tid = threadIdx.x, wave = tid >> 6, lane = tid & 63;
  const int nb = N >> 6;
  const int bm = (int)blockIdx.x / nb, bn = (int)blockIdx.x % nb;
  const int m0 = bm << 6, n0 = bn << 6;
  const int lrow = lane & 15, quad = lane >> 4;
  const int wm = (wave >> 1) << 5, wn = (wave & 1) << 5;
  const int srow = lane >> 3, scol = (lane & 7) << 3;

  f32x4 acc[2][2] = {};

  for (int kt = 0; kt < K; kt += 64) {
    __syncthreads();
#pragma unroll
    for (int i = 0; i < 2; ++i) {
      const int ci = i * 4 + wave;          // 8 chunks of 8 rows
      const int row = ci * 8 + srow;
      gload_lds16(A  + (long)(m0 + row) * K + kt + scol, (void*)&As[ci * 512]);
      gload_lds16(Bt + (long)(n0 + row) * K + kt + scol, (void*)&Bs[ci * 512]);
    }
    __syncthreads();
#pragma unroll
    for (int s = 0; s < 2; ++s) {
      short8 afr[2], bfr[2];
#pragma unroll
      for (int i = 0; i < 2; ++i)
        afr[i] = *(const short8*)&As[(wm + i * 16 + lrow) * 64 + s * 32 + quad * 8];
#pragma unroll
      for (int j = 0; j < 2; ++j)
        bfr[j] = *(const short8*)&Bs[(wn + j * 16 + lrow) * 64 + s * 32 + quad * 8];
#pragma unroll
      for (int i = 0; i < 2; ++i)
#pragma unroll
        for (int j = 0; j < 2; ++j)
          acc[i][j] = __builtin_amdgcn_mfma_f32_16x16x32_bf16(afr[i], bfr[j], acc[i][j], 0, 0, 0);
    }
  }

#pragma unroll
  for (int i = 0; i < 2; ++i) {
    const int rowb = m0 + wm + i * 16 + quad * 4;
#pragma unroll
    for (int j = 0; j < 2; ++j) {
      const int col = n0 + wn + j * 16 + lrow;
      const float bv = bias[col];
#pragma unroll
      for (int r = 0; r < 4; ++r) {
        const int row = rowb + r;
        float val = acc[i][j][r] + bv;
        if (MODE == 0) Cout[(long)row * N + col] = val;
        else           Cout[(long)col * M + row] = val * __expf(lng * (float)row);
      }
    }
  }
}

// ---------------------------------------------------------------------------
// RPE row op: srms -> relu -> bf16
// ---------------------------------------------------------------------------
__device__ __forceinline__ void srms_relu_store(float v0, float v1, ushort_t* out,
                                                long rowbase, int tid)
{
  float ss = v0 * v0 + v1 * v1;
#pragma unroll
  for (int off = 32; off; off >>= 1) ss += __shfl_down(ss, off);
  __shared__ float ps[4];
  const int wave = tid >> 6, lane = tid & 63;
  if (lane == 0) ps[wave] = ss;
  __syncthreads();
  float tot = ps[0] + ps[1] + ps[2] + ps[3];
  float sc = 1.f / (sqrtf(tot * (1.f / 512.f)) + 1e-6f);
  out[rowbase + tid]       = f2bf(fmaxf(v0 * sc, 0.f));
  out[rowbase + tid + 256] = f2bf(fmaxf(v1 * sc, 0.f));
}

__launch_bounds__(256)
__global__ void rpe_norm(const float* __restrict__ h, ushort_t* __restrict__ out)
{
  const int n = blockIdx.x, tid = threadIdx.x;
  float v0 = h[(long)n * 512 + tid];
  float v1 = h[(long)n * 512 + tid + 256];
  srms_relu_store(v0, v1, out, (long)n * 512, tid);
}

// ---------------------------------------------------------------------------
// Merged prep: 6x weight transpose | bias concat | x->bf16 | twiddles | rpe_h0
// ---------------------------------------------------------------------------
__device__ __forceinline__ void wtrans_body(const float* __restrict__ src,
                                            ushort_t* __restrict__ dst,
                                            int K, int N, int lb, int tid,
                                            float (*tile)[33])
{
  const int nbx = N >> 5;
  const int bx = lb % nbx, by = lb / nbx;
  const int n0 = bx << 5, k0 = by << 5;
  const int tx = tid & 31, ty = tid >> 5;
  for (int yy = ty; yy < 32; yy += 8)
    tile[yy][tx] = src[(long)(k0 + yy) * N + n0 + tx];
  __syncthreads();
  for (int yy = ty; yy < 32; yy += 8)
    dst[(long)(n0 + yy) * K + k0 + tx] = f2bf(tile[tx][yy]);
}

__launch_bounds__(256)
__global__ void prep_all(const float* __restrict__ Wu, const float* __restrict__ Wv,
                         const float* __restrict__ Wo, const float* __restrict__ rW,
                         const float* __restrict__ rWout,
                         const float* __restrict__ bu, const float* __restrict__ bv,
                         const float* __restrict__ x,
                         const float* __restrict__ rWin, const float* __restrict__ rbin,
                         ushort_t* __restrict__ wuvt, ushort_t* __restrict__ wot,
                         ushort_t* __restrict__ wrt, ushort_t* __restrict__ wroutt,
                         float* __restrict__ buvb, ushort_t* __restrict__ xb,
                         float2* __restrict__ twg, float2* __restrict__ twh,
                         ushort_t* __restrict__ a0)
{
  __shared__ float tile[32][33];
  const int bid = blockIdx.x, tid = threadIdx.x;
  if (bid < 3840) {
    const float* src; ushort_t* dst; int K, N, lb;
    if (bid < 768)       { src = Wu;    dst = wuvt;              K = 512;  N = 1536; lb = bid; }
    else if (bid < 1536) { src = Wv;    dst = wuvt + 1536L*512;  K = 512;  N = 1536; lb = bid - 768; }
    else if (bid < 2304) { src = Wo;    dst = wot;               K = 1536; N = 512;  lb = bid - 1536; }
    else if (bid < 2560) { src = rW;              dst = wrt;              K = 512; N = 512; lb = bid - 2304; }
    else if (bid < 2816) { src = rW + 512L*512;   dst = wrt + 512L*512;   K = 512; N = 512; lb = bid - 2560; }
    else if (bid < 3072) { src = rW + 2L*512*512; dst = wrt + 2L*512*512; K = 512; N = 512; lb = bid - 2816; }
    else                 { src = rWout; dst = wroutt;            K = 512;  N = 1536; lb = bid - 3072; }
    wtrans_body(src, dst, K, N, lb, tid, tile);
  } else if (bid < 3846) {
    int i = (bid - 3840) * 256 + tid;
    if (i < 1536) { buvb[i] = bu[i]; buvb[1536 + i] = bv[i]; }
  } else if (bid < 12038) {
    long i = (long)(bid - 3846) * 1024 + tid * 4;
    float4 f = *(const float4*)(x + i);
    unsigned lo = (unsigned)f2bf(f.x) | ((unsigned)f2bf(f.y) << 16);
    unsigned hi = (unsigned)f2bf(f.z) | ((unsigned)f2bf(f.w) << 16);
    *(uint2*)(xb + i) = make_uint2(lo, hi);
  } else if (bid < 12046) {
    int j = (bid - 12038) * 256 + tid;    // 0..2047
    float s, c;
    __sincosf((float)j * (6.283185307179586f / 2048.f), &s, &c);
    twg[j] = make_float2(c, -s);
    float s2, c2;
    __sincosf((float)j * (3.14159265358979f / 2048.f), &s2, &c2);
    twh[j] = make_float2(c2, -s2);
  } else {
    const int n = bid - 12046;            // 0..2047
    const float fn = (float)n;
    float v0 = fn * rWin[tid] + rbin[tid];
    float v1 = fn * rWin[tid + 256] + rbin[tid + 256];
    srms_relu_store(v0, v1, a0, (long)n * 512, tid);
  }
}

// ---------------------------------------------------------------------------
// Block-level Stockham FFT-2048 (radix 8,8,8,4), TWO sequences at once.
// Identical index math to R4's HW-verified fft2048_r8; registers duplicated,
// twiddles shared, one barrier set for both. In b0*, scratch b1*, out b0*.
// ---------------------------------------------------------------------------
__device__ __forceinline__ float2 cmulf(float2 a, float2 b) {
  return make_float2(a.x * b.x - a.y * b.y, a.x * b.y + a.y * b.x);
}
__device__ __forceinline__ float2 cadd(float2 a, float2 b){ return make_float2(a.x+b.x, a.y+b.y); }
__device__ __forceinline__ float2 csub(float2 a, float2 b){ return make_float2(a.x-b.x, a.y-b.y); }
__device__ __forceinline__ float2 cmni(float2 z){ return make_float2(z.y, -z.x); }     // z * (-i)
__device__ __forceinline__ float2 cw8(float2 z){   // z * cis(-pi/4)
  const float s = 0.70710678118654752f;
  return make_float2(s*(z.x+z.y), s*(z.y-z.x));
}
__device__ __forceinline__ float2 cw83(float2 z){  // z * cis(-3pi/4)
  const float s = 0.70710678118654752f;
  return make_float2(s*(z.y-z.x), -s*(z.x+z.y));
}

// DFT-8 combine (twiddles pre-applied) [R4 HW-verified]
__device__ __forceinline__ void dft8(const float2* u, float2* y)
{
  float2 a0=cadd(u[0],u[4]), a1=cadd(u[1],u[5]), a2=cadd(u[2],u[6]), a3=cadd(u[3],u[7]);
  float2 b0=csub(u[0],u[4]), b1=cw8(csub(u[1],u[5])), b2=cmni(csub(u[2],u[6])), b3=cw83(csub(u[3],u[7]));
  float2 c0=cadd(a0,a2), c1=csub(a0,a2), c2=cadd(a1,a3), c3=cmni(csub(a1,a3));
  y[0]=cadd(c0,c2); y[2]=cadd(c1,c3); y[4]=csub(c0,c2); y[6]=csub(c1,c3);
  float2 d0=cadd(b0,b2), d1=csub(b0,b2), d2=cadd(b1,b3), d3=cmni(csub(b1,b3));
  y[1]=cadd(d0,d2); y[3]=cadd(d1,d3); y[5]=csub(d0,d2); y[7]=csub(d1,d3);
}
__device__ __forceinline__ void dft8_hz(const float2* u, float2* y)   // u[4..7]=0
{
  float2 b1=cw8(u[1]), b2=cmni(u[2]), b3=cw83(u[3]);
  float2 c0=cadd(u[0],u[2]), c1=csub(u[0],u[2]), c2=cadd(u[1],u[3]), c3=cmni(csub(u[1],u[3]));
  y[0]=cadd(c0,c2); y[2]=cadd(c1,c3); y[4]=csub(c0,c2); y[6]=csub(c1,c3);
  float2 d0=cadd(u[0],b2), d1=csub(u[0],b2), d2=cadd(b1,b3), d3=cmni(csub(b1,b3));
  y[1]=cadd(d0,d2); y[3]=cadd(d1,d3); y[5]=csub(d0,d2); y[7]=csub(d1,d3);
}

template<bool HZ>
__device__ void fft2048_r8_2(float2* b0a, float2* b1a, float2* b0b, float2* b1b,
                             const float2* __restrict__ tw, int tid)
{
  float2 u[8], v[8], y[8], z[8];
  // ---- stage 1: radix-8, p=1 (no twiddles) ----
  {
    const int i = tid;
#pragma unroll
    for (int m = 0; m < (HZ ? 4 : 8); ++m) { u[m] = b0a[i + 256*m]; v[m] = b0b[i + 256*m]; }
    if (HZ) { dft8_hz(u, y); dft8_hz(v, z); } else { dft8(u, y); dft8(v, z); }
    const int j = i << 3;
#pragma unroll
    for (int m = 0; m < 8; ++m) { b1a[SW1(j + m)] = y[m]; b1b[SW1(j + m)] = z[m]; }
  }
  __syncthreads();
  // ---- stage 2: radix-8, p=8 (tw step 32) ----
  {
    const int i = tid, k = i & 7, tb = k << 5;
    float2 w[8];
#pragma unroll
    for (int m = 1; m < 8; ++m) w[m] = tw[m * tb];
#pragma unroll
    for (int m = 0; m < 8; ++m) { u[m] = b1a[SW1(i + 256*m)]; v[m] = b1b[SW1(i + 256*m)]; }
#pragma unroll
    for (int m = 1; m < 8; ++m) { u[m] = cmulf(u[m], w[m]); v[m] = cmulf(v[m], w[m]); }
    dft8(u, y); dft8(v, z);
    const int j = ((i - k) << 3) + k;
#pragma unroll
    for (int m = 0; m < 8; ++m) { b0a[SW2(j + 8*m)] = y[m]; b0b[SW2(j + 8*m)] = z[m]; }
  }
  __syncthreads();
  // ---- stage 3: radix-8, p=64 (tw step 4) ----
  {
    const int i = tid, k = i & 63, tb = k << 2;
    float2 w[8];
#pragma unroll
    for (int m = 1; m < 8; ++m) w[m] = tw[m * tb];
#pragma unroll
    for (int m = 0; m < 8; ++m) { u[m] = b0a[SW2(i + 256*m)]; v[m] = b0b[SW2(i + 256*m)]; }
#pragma unroll
    for (int m = 1; m < 8; ++m) { u[m] = cmulf(u[m], w[m]); v[m] = cmulf(v[m], w[m]); }
    dft8(u, y); dft8(v, z);
    const int j = ((i - k) << 3) + k;
#pragma unroll
    for (int m = 0; m < 8; ++m) { b1a[j + 64*m] = y[m]; b1b[j + 64*m] = z[m]; }
  }
  __syncthreads();
  // ---- stage 4: radix-4, p=512 (k=i, j=i) ----
#pragma unroll
  for (int hh = 0; hh < 2; ++hh) {
    const int i = tid + (hh << 8);
    float2 w1 = tw[i], w2 = tw[2 * i], w3 = tw[3 * i];
    float2 q0 = b1a[i], q1 = b1a[i + 512], q2 = b1a[i + 1024], q3 = b1a[i + 1536];
    float2 r0 = b1b[i], r1 = b1b[i + 512], r2 = b1b[i + 1024], r3 = b1b[i + 1536];
    q1 = cmulf(q1, w1); q2 = cmulf(q2, w2); q3 = cmulf(q3, w3);
    r1 = cmulf(r1, w1); r2 = cmulf(r2, w2); r3 = cmulf(r3, w3);
    {
      float2 v0 = cadd(q0, q2), v2 = csub(q0, q2);
      float2 v1 = cadd(q1, q3), v3 = cmni(csub(q1, q3));
      b0a[i]        = cadd(v0, v1);
      b0a[i + 512]  = cadd(v2, v3);
      b0a[i + 1024] = csub(v0, v1);
      b0a[i + 1536] = csub(v2, v3);
    }
    {
      float2 v0 = cadd(r0, r2), v2 = csub(r0, r2);
      float2 v1 = cadd(r1, r3), v3 = cmni(csub(r1, r3));
      b0b[i]        = cadd(v0, v1);
      b0b[i + 512]  = cadd(v2, v3);
      b0b[i + 1024] = csub(v0, v1);
      b0b[i + 1536] = csub(v2, v3);
    }
  }
  __syncthreads();
}

// Kernel spectrum, 2 channels/block: af[c][k] = rfft_4096(kern[c] zero-padded)
__launch_bounds__(256, 2)
__global__ void fft_kernel_spec(const float* __restrict__ kern, float2* __restrict__ af,
                                const float2* __restrict__ twg, const float2* __restrict__ twh)
{
  __shared__ float2 bx0[2048], by0[2048], bx1[2048], by1[2048];
  const int tid = threadIdx.x;
  const int c0 = (int)blockIdx.x * 2;
  const float* ka = kern + (long)c0 * 2048;
  const float* kb = ka + 2048;
  for (int j = tid; j < 1024; j += 256) {
    bx0[j] = *(const float2*)(ka + 2 * j);
    bx1[j] = *(const float2*)(kb + 2 * j);
  }
  __syncthreads();
  fft2048_r8_2<true>(bx0, by0, bx1, by1, twg, tid);
  float2* af0 = af + (long)c0 * 2052;
  float2* af1 = af0 + 2052;
  for (int k = tid; k <= 1024; k += 256) {
    const float2 W = twh[k];
    const int kn = (2048 - k) & 2047;
    {
      float2 Zk = bx0[k], Zn = bx0[kn];
      float2 E = make_float2(0.5f * (Zk.x + Zn.x), 0.5f * (Zk.y - Zn.y));
      float2 O = make_float2(0.5f * (Zk.y + Zn.y), 0.5f * (Zn.x - Zk.x));
      float2 WO = cmulf(W, O);
      af0[k] = make_float2(E.x + WO.x, E.y + WO.y);
      if (k != 0 && k != 1024) af0[2048 - k] = make_float2(E.x - WO.x, -(E.y - WO.y));
      if (k == 0)              af0[2048]     = make_float2(E.x - WO.x, -(E.y - WO.y));
    }
    {
      float2 Zk = bx1[k], Zn = bx1[kn];
      float2 E = make_float2(0.5f * (Zk.x + Zn.x), 0.5f * (Zk.y - Zn.y));
      float2 O = make_float2(0.5f * (Zk.y + Zn.y), 0.5f * (Zn.x - Zk.x));
      float2 WO = cmulf(W, O);
      af1[k] = make_float2(E.x + WO.x, E.y + WO.y);
      if (k != 0 && k != 1024) af1[2048 - k] = make_float2(E.x - WO.x, -(E.y - WO.y));
      if (k == 0)              af1[2048]     = make_float2(E.x - WO.x, -(E.y - WO.y));
    }
  }
}

// Conv (IN PLACE on vt), 2 sequences/block (always same channel: 8 seq/chan,
// even-aligned pairs): y = irfft4096(rfft4096(v)*af)[0:2048]
__launch_bounds__(256, 2)
__global__ void fft_conv(ushort_t* __restrict__ vt, const float2* __restrict__ af,
                         const float2* __restrict__ twg, const float2* __restrict__ twh)
{
  __shared__ float2 bx0[2048], by0[2048], bx1[2048], by1[2048];
  const int tid = threadIdx.x;
  const long s0 = (long)blockIdx.x * 2;
  const int c = (int)(s0 >> 3);
  ushort_t* vsa = vt + s0 * 2048;
  ushort_t* vsb = vsa + 2048;
#pragma unroll
  for (int jj = 0; jj < 4; ++jj) {
    const int j = tid + jj * 256;
    unsigned pa = *(const unsigned*)(vsa + 2 * j);
    unsigned pb = *(const unsigned*)(vsb + 2 * j);
    bx0[j] = make_float2(bf2f((ushort_t)(pa & 0xffffu)), bf2f((ushort_t)(pa >> 16)));
    bx1[j] = make_float2(bf2f((ushort_t)(pb & 0xffffu)), bf2f((ushort_t)(pb >> 16)));
  }
  __syncthreads();
  fft2048_r8_2<true>(bx0, by0, bx1, by1, twg, tid);   // bx* = Z (packed fwd FFT)
  const float2* afc = af + (long)c * 2052;
  for (int k = tid; k <= 1024; k += 256) {
    const float2 A0 = afc[k], A1 = afc[2048 - k], W = twh[k];
    const float2 cW = make_float2(W.x, -W.y);
    const int kn = (2048 - k) & 2047;
    {
      float2 Zk = bx0[k], Zn = bx0[kn];
      float2 E = make_float2(0.5f * (Zk.x + Zn.x), 0.5f * (Zk.y - Zn.y));
      float2 O = make_float2(0.5f * (Zk.y + Zn.y), 0.5f * (Zn.x - Zk.x));
      float2 WO = cmulf(W, O);
      float2 Xk = make_float2(E.x + WO.x, E.y + WO.y);
      float2 Xn = make_float2(E.x - WO.x, -(E.y - WO.y));
      float2 Pk = cmulf(Xk, A0);
      float2 Pn = cmulf(Xn, A1);
      float2 E2 = make_float2(0.5f * (Pk.x + Pn.x), 0.5f * (Pk.y - Pn.y));
      float2 G  = make_float2(0.5f * (Pk.x - Pn.x), 0.5f * (Pk.y + Pn.y));
      float2 Fo = cmulf(cW, G);
      by0[k] = make_float2(E2.x - Fo.y, -(E2.y + Fo.x));
      if (k != 0 && k != 1024)
        by0[2048 - k] = make_float2(E2.x + Fo.y, E2.y - Fo.x);
    }
    {
      float2 Zk = bx1[k], Zn = bx1[kn];
      float2 E = make_float2(0.5f * (Zk.x + Zn.x), 0.5f * (Zk.y - Zn.y));
      float2 O = make_float2(0.5f * (Zk.y + Zn.y), 0.5f * (Zn.x - Zk.x));
      float2 WO = cmulf(W, O);
      float2 Xk = make_float2(E.x + WO.x, E.y + WO.y);
      float2 Xn = make_float2(E.x - WO.x, -(E.y - WO.y));
      float2 Pk = cmulf(Xk, A0);
      float2 Pn = cmulf(Xn, A1);
      float2 E2 = make_float2(0.5f * (Pk.x + Pn.x), 0.5f * (Pk.y - Pn.y));
      float2 G  = make_float2(0.5f * (Pk.x - Pn.x), 0.5f * (Pk.y + Pn.y));
      float2 Fo = cmulf(cW, G);
      by1[k] = make_float2(E2.x - Fo.y, -(E2.y + Fo.x));
      if (k != 0 && k != 1024)
        by1[2048 - k] = make_float2(E2.x + Fo.y, E2.y - Fo.x);
    }
  }
  __syncthreads();
  fft2048_r8_2<false>(by0, bx0, by1, bx1, twg, tid);  // by* = FFT(conj(W2))
  const float inv = 1.f / 2048.f;
#pragma unroll
  for (int jj = 0; jj < 4; ++jj) {                    // z[j]=conj(by[j])/2048
    const int j = tid + jj * 256;
    float2 ra = by0[j], rb = by1[j];
    unsigned oa = (unsigned)f2bf(ra.x * inv) | ((unsigned)f2bf(-ra.y * inv) << 16);
    unsigned ob = (unsigned)f2bf(rb.x * inv) | ((unsigned)f2bf(-rb.y * inv) << 16);
    *(unsigned*)(vsa + 2 * j) = oa;
    *(unsigned*)(vsb + 2 * j) = ob;
  }
}

// gate IN PLACE: u[bn][c] *= conv[c][bn]   (conv lives in vt)
__launch_bounds__(256)
__global__ void gate_trans(const ushort_t* __restrict__ convt, ushort_t* __restrict__ u)
{
  __shared__ ushort_t tile[64][65];
  const int bc = (int)blockIdx.x % 24, br = (int)blockIdx.x / 24;
  const int c0 = bc << 6, r0 = br << 6;
  const int tx = threadIdx.x & 63, ty = threadIdx.x >> 6;
  for (int yy = ty; yy < 64; yy += 4)
    tile[yy][tx] = convt[(long)(c0 + yy) * 16384 + r0 + tx];
  __syncthreads();
  for (int yy = ty; yy < 64; yy += 4) {
    long ui = (long)(r0 + yy) * 1536 + c0 + tx;
    float uu = bf2f(u[ui]);
    float cc = bf2f(tile[tx][yy]);
    u[ui] = f2bf(uu * cc);
  }
}

// ===========================================================================
extern "C" void kernel_launch(void* const* d_in, const int* in_sizes, int n_in,
                              void* d_out, int out_size, void* d_ws, size_t ws_size,
                              hipStream_t stream)
{
  const float* x     = (const float*)d_in[0];
  const float* Wu    = (const float*)d_in[1];
  const float* bu    = (const float*)d_in[2];
  const float* Wv    = (const float*)d_in[3];
  const float* bv    = (const float*)d_in[4];
  const float* Wo    = (const float*)d_in[5];
  const float* bo    = (const float*)d_in[6];
  const float* rWin  = (const float*)d_in[7];
  const float* rbin  = (const float*)d_in[8];
  const float* rW    = (const float*)d_in[9];
  const float* rb    = (const float*)d_in[10];
  const float* rWout = (const float*)d_in[11];
  const float* rbout = (const float*)d_in[12];

  char* base = (char*)d_ws;
  size_t off = 0;
  auto alloc = [&](size_t bytes) -> char* {
    size_t r = (off + 255) & ~(size_t)255; off = r + bytes; return base + r;
  };
  ushort_t* wuvt   = (ushort_t*)alloc(3072L * 512 * 2);     // [Wu^T; Wv^T]  3MB
  ushort_t* wot    = (ushort_t*)alloc(512L * 1536 * 2);     // Wo^T        1.5MB
  ushort_t* wrt    = (ushort_t*)alloc(3L * 512 * 512 * 2);  // rpe_W^T x3  1.5MB
  ushort_t* wroutt = (ushort_t*)alloc(1536L * 512 * 2);     // rpe_Wout^T  1.5MB
  float*    buvb   = (float*)   alloc(3072L * 4);           // [bu;bv]
  ushort_t* a0     = (ushort_t*)alloc(2048L * 512 * 2);     // RPE act bf16  2MB
  float2*   af     = (float2*)  alloc(1536L * 2052 * 8);    // spectra    25.2MB
  float2*   twg    = (float2*)  alloc(2048L * 8);           // cis(-2pi j/2048)
  float2*   twh    = (float2*)  alloc(2048L * 8);           // cis(-pi k/2048)
  char*     X      = alloc(16384L * 512 * 2);               // xb | (h+kern) 16MB
  ushort_t* u      = (ushort_t*)alloc(16384L * 1536 * 2);   // u (later gated) 48MB
  ushort_t* vt     = (ushort_t*)alloc(1536L * 16384 * 2);   // v^T / conv^T  48MB
  ushort_t* xb   = (ushort_t*)X;
  float*    h    = (float*)X;
  float*    kern = (float*)(X + 4L * 1024 * 1024);

  const float lng = -0.01005033585350145f;   // ln(0.99)

  // ---- merged prep: weights, biases, x->bf16, twiddles, rpe_h0 ----
  prep_all<<<dim3(14094), dim3(256), 0, stream>>>(
      Wu, Wv, Wo, rW, rWout, bu, bv, x, rWin, rbin,
      wuvt, wot, wrt, wroutt, buvb, xb, twg, twh, a0);

  // ---- u/v projection (fused, v stored transposed) ----
  gemm_bt<3><<<dim3(3072), dim3(256), 0, stream>>>(xb, wuvt, buvb, u, vt,
                                                   16384, 3072, 512, 0.f);

  // ---- RPE chain -> kern[c][n] -> spectra af ----
  for (int i = 0; i < 3; ++i) {
    gemm64_bt<0><<<dim3(256), dim3(256), 0, stream>>>(a0, wrt + (long)i * 512 * 512,
                                                      rb + (long)i * 512, h,
                                                      2048, 512, 512, 0.f);
    rpe_norm<<<dim3(2048), dim3(256), 0, stream>>>(h, a0);
  }
  gemm64_bt<2><<<dim3(768), dim3(256), 0, stream>>>(a0, wroutt, rbout, kern,
                                                    2048, 1536, 512, lng);
  fft_kernel_spec<<<dim3(768), dim3(256), 0, stream>>>(kern, af, twg, twh);

  // ---- FFT conv in place on vt, gate in place into u, out projection ----
  fft_conv<<<dim3(6144), dim3(256), 0, stream>>>(vt, af, twg, twh);
  gate_trans<<<dim3(6144), dim3(256), 0, stream>>>(vt, u);
  gemm_bt<0><<<dim3(512), dim3(256), 0, stream>>>(u, wot, bo, d_out, nullptr,
                                                  16384, 512, 1536, 0.f);
}